// Round 6
// baseline (156.759 us; speedup 1.0000x reference)
//
#include <hip/hip_runtime.h>
#include <math.h>

#define NCH    1024
#define NN     64
#define CK     32                    // fused-fallback chunk
#define KSC    28.853900817779268f   // 20*log2(e): exp(-cost/0.05) = 2^((sim-1)*KSC)
#define SPLIT  2                     // records per batch in ws
#define WSB    4352                  // floats per record: 4096 gram + 4*64 stats

// ===================== Kernel A: software-pipelined direct-global Gram =====================
// grid = 1024 blocks x 256 thr (4 waves). Block (b,h); wave w owns channels
// [h*512 + w*128, +128). Lane (ri,ci) accumulates an 8x8 Gram tile reading q/p
// straight from global (intra-wave broadcast). 4 register slots, 3-deep
// in-flight pipeline, no LDS and no barriers until the merge.
__global__ __launch_bounds__(256)
void gram4(const float* __restrict__ proto,
           const float* __restrict__ query,
           float* __restrict__ ws)
{
    __shared__ __align__(16) float GA[4096];        // waves 0,1
    __shared__ __align__(16) float GB[4096];        // waves 2,3
    __shared__ __align__(16) float st4[4 * 4 * NN]; // [stat][wave][node]

    const int bid = blockIdx.x;
    const int b = bid >> 1, h = bid & 1;
    const int t = threadIdx.x;
    const int w = t >> 6;            // wave 0..3
    const int l = t & 63;
    const int ri = l >> 3;
    const int ci = l & 7;
    const int r0 = ri * 8;           // q rows owned
    const int c0 = ci * 4;           // p cols owned: c0..c0+3, c0+32..c0+35

    const float* __restrict__ qw = query + (size_t)b * 65536 + (h * 512 + w * 128) * 64;
    const float* __restrict__ pw = proto + (size_t)b * 65536 + (h * 512 + w * 128) * 64;

    float acc[8][8];
    #pragma unroll
    for (int i = 0; i < 8; ++i)
        #pragma unroll
        for (int j = 0; j < 8; ++j) acc[i][j] = 0.0f;
    float sq = 0.0f, q2 = 0.0f, sp = 0.0f, p2 = 0.0f;

    float4 A0[4], A1[4], B0[4], B1[4];
    float  QS[4], PS[4];

#define LOADSLOT(K, C) do {                                   \
        const float* qc_ = qw + (C) * 64;                     \
        const float* pc_ = pw + (C) * 64;                     \
        A0[K] = *(const float4*)(qc_ + r0);                   \
        A1[K] = *(const float4*)(qc_ + r0 + 4);               \
        B0[K] = *(const float4*)(pc_ + c0);                   \
        B1[K] = *(const float4*)(pc_ + c0 + 32);              \
        QS[K] = qc_[l];                                       \
        PS[K] = pc_[l];                                       \
    } while (0)

#define COMPUTESLOT(K) do {                                   \
        const float av[8] = {A0[K].x,A0[K].y,A0[K].z,A0[K].w, \
                             A1[K].x,A1[K].y,A1[K].z,A1[K].w};\
        const float bv[8] = {B0[K].x,B0[K].y,B0[K].z,B0[K].w, \
                             B1[K].x,B1[K].y,B1[K].z,B1[K].w};\
        sq += QS[K]; q2 = fmaf(QS[K], QS[K], q2);             \
        sp += PS[K]; p2 = fmaf(PS[K], PS[K], p2);             \
        _Pragma("unroll")                                     \
        for (int i = 0; i < 8; ++i)                           \
            _Pragma("unroll")                                 \
            for (int j = 0; j < 8; ++j)                       \
                acc[i][j] = fmaf(av[i], bv[j], acc[i][j]);    \
    } while (0)

    LOADSLOT(0, 0); LOADSLOT(1, 1); LOADSLOT(2, 2); LOADSLOT(3, 3);

    #pragma unroll 1
    for (int g = 0; g < 31; ++g) {
        const int c = g * 4;
        COMPUTESLOT(0); LOADSLOT(0, c + 4);
        COMPUTESLOT(1); LOADSLOT(1, c + 5);
        COMPUTESLOT(2); LOADSLOT(2, c + 6);
        COMPUTESLOT(3); LOADSLOT(3, c + 7);
    }
    COMPUTESLOT(0); COMPUTESLOT(1); COMPUTESLOT(2); COMPUTESLOT(3);
#undef LOADSLOT
#undef COMPUTESLOT

    // stats: lane l holds node l's partial for this wave
    st4[(0*4 + w)*NN + l] = sq;
    st4[(1*4 + w)*NN + l] = q2;
    st4[(2*4 + w)*NN + l] = sp;
    st4[(3*4 + w)*NN + l] = p2;

    // ---- merge: waves 0,2 store; waves 1,3 accumulate ----
    {
        float* const GT = (w < 2) ? GA : GB;
        const bool first = ((w & 1) == 0);
        if (first) {
            #pragma unroll
            for (int i = 0; i < 8; ++i) {
                float4 v0; v0.x=acc[i][0]; v0.y=acc[i][1]; v0.z=acc[i][2]; v0.w=acc[i][3];
                float4 v1; v1.x=acc[i][4]; v1.y=acc[i][5]; v1.z=acc[i][6]; v1.w=acc[i][7];
                *(float4*)&GT[(r0 + i) * 64 + c0]      = v0;
                *(float4*)&GT[(r0 + i) * 64 + c0 + 32] = v1;
            }
        }
        __syncthreads();
        if (!first) {
            #pragma unroll
            for (int i = 0; i < 8; ++i) {
                float* g0 = &GT[(r0 + i) * 64 + c0];
                float* g1 = &GT[(r0 + i) * 64 + c0 + 32];
                float4 d0 = *(const float4*)g0;
                float4 d1 = *(const float4*)g1;
                d0.x+=acc[i][0]; d0.y+=acc[i][1]; d0.z+=acc[i][2]; d0.w+=acc[i][3];
                d1.x+=acc[i][4]; d1.y+=acc[i][5]; d1.z+=acc[i][6]; d1.w+=acc[i][7];
                *(float4*)g0 = d0;
                *(float4*)g1 = d1;
            }
        }
        __syncthreads();
    }

    // ---- write record: 16 gram floats per thread + stats by t<64 ----
    float* __restrict__ wsb = ws + (size_t)bid * WSB;
    {
        const int base = t * 16;
        #pragma unroll
        for (int k = 0; k < 4; ++k) {
            float4 x = *(const float4*)&GA[base + k * 4];
            float4 y = *(const float4*)&GB[base + k * 4];
            x.x+=y.x; x.y+=y.y; x.z+=y.z; x.w+=y.w;
            *(float4*)&wsb[base + k * 4] = x;
        }
    }
    if (t < NN) {
        #pragma unroll
        for (int k = 0; k < 4; ++k) {
            float s = st4[(k*4 + 0)*NN + t] + st4[(k*4 + 1)*NN + t]
                    + st4[(k*4 + 2)*NN + t] + st4[(k*4 + 3)*NN + t];
            wsb[4096 + k * 64 + t] = s;
        }
    }
}

#define DOT16(KK, ARR) ({ \
    float4 x0 = *(const float4*)&ARR[sp4*16 +  0]; \
    float4 x1 = *(const float4*)&ARR[sp4*16 +  4]; \
    float4 x2 = *(const float4*)&ARR[sp4*16 +  8]; \
    float4 x3 = *(const float4*)&ARR[sp4*16 + 12]; \
    float a0 = 0.0f, a1 = 0.0f; \
    a0=fmaf(KK[0],x0.x,a0);  a1=fmaf(KK[1],x0.y,a1); \
    a0=fmaf(KK[2],x0.z,a0);  a1=fmaf(KK[3],x0.w,a1); \
    a0=fmaf(KK[4],x1.x,a0);  a1=fmaf(KK[5],x1.y,a1); \
    a0=fmaf(KK[6],x1.z,a0);  a1=fmaf(KK[7],x1.w,a1); \
    a0=fmaf(KK[8],x2.x,a0);  a1=fmaf(KK[9],x2.y,a1); \
    a0=fmaf(KK[10],x2.z,a0); a1=fmaf(KK[11],x2.w,a1); \
    a0=fmaf(KK[12],x3.x,a0); a1=fmaf(KK[13],x3.y,a1); \
    a0=fmaf(KK[14],x3.z,a0); a1=fmaf(KK[15],x3.w,a1); \
    a0 + a1; })

// ===================== Kernel B: combine + sim + K + Sinkhorn + logits =====================
__global__ __launch_bounds__(256)
void emd_solve(const float* __restrict__ ws, float* __restrict__ out)
{
    __shared__ __align__(16) float stage[16 * 64];
    __shared__ __align__(16) float Kl [NN][68];
    __shared__ __align__(16) float KTl[NN][68];
    __shared__ __align__(16) float statL[4][NN];
    __shared__ __align__(16) float uL[NN];
    __shared__ __align__(16) float vL[NN];
    __shared__ __align__(16) float rL[NN];
    __shared__ __align__(16) float cL[NN];
    __shared__ float redl[4];

    const int b  = blockIdx.x;
    const int t  = threadIdx.x;
    const int tr = t >> 4, tc = t & 15;
    const int n0 = tr * 4, m0 = tc * 4;

    const float* __restrict__ wsb = ws + (size_t)b * SPLIT * WSB;

    float acc[4][4];
    #pragma unroll
    for (int i = 0; i < 4; ++i)
        #pragma unroll
        for (int j = 0; j < 4; ++j) acc[i][j] = 0.0f;
    #pragma unroll
    for (int s = 0; s < SPLIT; ++s) {
        const float* __restrict__ g = wsb + s * WSB;
        #pragma unroll
        for (int i = 0; i < 4; ++i) {
            float4 v = *(const float4*)&g[(n0 + i) * 64 + m0];
            acc[i][0] += v.x; acc[i][1] += v.y; acc[i][2] += v.z; acc[i][3] += v.w;
        }
    }
    if (t < NN) {
        float s0 = 0, s1 = 0, s2 = 0, s3 = 0;
        #pragma unroll
        for (int s = 0; s < SPLIT; ++s) {
            const float* __restrict__ g = wsb + s * WSB + 4096;
            s0 += g[t]; s1 += g[64 + t]; s2 += g[128 + t]; s3 += g[192 + t];
        }
        statL[0][t] = s0; statL[1][t] = s1; statL[2][t] = s2; statL[3][t] = s3;
    }
    #pragma unroll
    for (int i = 0; i < 4; ++i) {
        float s = acc[i][0] + acc[i][1] + acc[i][2] + acc[i][3];
        s += __shfl_xor(s, 1, 64); s += __shfl_xor(s, 2, 64);
        s += __shfl_xor(s, 4, 64); s += __shfl_xor(s, 8, 64);
        if (tc == 0) uL[n0 + i] = s;
    }
    #pragma unroll
    for (int j = 0; j < 4; ++j)
        stage[tr * 64 + m0 + j] = acc[0][j] + acc[1][j] + acc[2][j] + acc[3][j];
    __syncthreads();

    if (t < NN) {
        float cs = 0;
        #pragma unroll
        for (int i = 0; i < 16; ++i) cs += stage[i * 64 + t];
        float w2 = fmaxf(cs * (1.0f/64.0f), 0.0f) + 0.001f;
        float w1 = fmaxf(uL[t] * (1.0f/64.0f), 0.0f) + 0.001f;
        float s1 = w1, s2 = w2;
        #pragma unroll
        for (int m = 1; m < 64; m <<= 1) {
            s1 += __shfl_xor(s1, m, 64);
            s2 += __shfl_xor(s2, m, 64);
        }
        rL[t] = w1 / s1;
        cL[t] = w2 / s2;
        vL[t] = 1.0f;
    }
    {
        float nq_[4], np_[4], sqn[4], spm[4];
        #pragma unroll
        for (int i = 0; i < 4; ++i) {
            float sv  = statL[0][n0 + i];
            float var = statL[1][n0 + i] - sv * sv * (1.0f/1024.0f);
            nq_[i] = fmaxf(sqrtf(fmaxf(var, 0.0f)), 1e-8f);
            sqn[i] = sv;
        }
        #pragma unroll
        for (int j = 0; j < 4; ++j) {
            float sv  = statL[2][m0 + j];
            float var = statL[3][m0 + j] - sv * sv * (1.0f/1024.0f);
            np_[j] = fmaxf(sqrtf(fmaxf(var, 0.0f)), 1e-8f);
            spm[j] = sv;
        }
        #pragma unroll
        for (int i = 0; i < 4; ++i) {
            #pragma unroll
            for (int j = 0; j < 4; ++j) {
                float sim = (acc[i][j] - sqn[i] * spm[j] * (1.0f/1024.0f)) / (nq_[i] * np_[j]);
                acc[i][j] = sim;
                float Kv = exp2f((sim - 1.0f) * KSC);
                Kl [n0 + i][m0 + j] = Kv;
                KTl[m0 + j][n0 + i] = Kv;
            }
        }
    }
    __syncthreads();

    const int sn  = t >> 2;
    const int sp4 = t & 3;
    float Kr[16], KTr[16];
    #pragma unroll
    for (int jj = 0; jj < 4; ++jj) {
        float4 kv = *(const float4*)&Kl [sn][sp4 * 16 + jj * 4];
        float4 kt = *(const float4*)&KTl[sn][sp4 * 16 + jj * 4];
        Kr [jj*4+0]=kv.x; Kr [jj*4+1]=kv.y; Kr [jj*4+2]=kv.z; Kr [jj*4+3]=kv.w;
        KTr[jj*4+0]=kt.x; KTr[jj*4+1]=kt.y; KTr[jj*4+2]=kt.z; KTr[jj*4+3]=kt.w;
    }
    const float rreg = rL[sn];
    const float creg = cL[sn];

    for (int it = 0; it < 100; ++it) {
        float s = DOT16(Kr, vL);
        s += __shfl_xor(s, 1, 64); s += __shfl_xor(s, 2, 64);
        float u = rreg / fmaxf(s, 1e-30f);
        if (sp4 == 0) uL[sn] = u;
        __syncthreads();
        float s2 = DOT16(KTr, uL);
        s2 += __shfl_xor(s2, 1, 64); s2 += __shfl_xor(s2, 2, 64);
        float vv = creg / fmaxf(s2, 1e-30f);
        if (sp4 == 0) vL[sn] = vv;
        __syncthreads();
    }
    {
        float s = DOT16(Kr, vL);
        s += __shfl_xor(s, 1, 64); s += __shfl_xor(s, 2, 64);
        float u = rreg / fmaxf(s, 1e-30f);
        if (sp4 == 0) uL[sn] = u;
    }
    __syncthreads();

    float uu[4], vv_[4];
    #pragma unroll
    for (int i = 0; i < 4; ++i) uu[i]  = uL[n0 + i];
    #pragma unroll
    for (int j = 0; j < 4; ++j) vv_[j] = vL[m0 + j];
    float part = 0.0f;
    #pragma unroll
    for (int i = 0; i < 4; ++i) {
        #pragma unroll
        for (int j = 0; j < 4; ++j) {
            float sim = acc[i][j];
            float Kv  = exp2f((sim - 1.0f) * KSC);
            part = fmaf(sim * Kv, uu[i] * vv_[j], part);
        }
    }
    #pragma unroll
    for (int m = 1; m < 64; m <<= 1) part += __shfl_xor(part, m, 64);
    if ((t & 63) == 0) redl[t >> 6] = part;
    __syncthreads();
    if (t == 0) out[b] = (redl[0] + redl[1] + redl[2] + redl[3]) * (12.5f / 64.0f);
}

// ===================== Fallback: verified fused single-kernel path =====================
#define STAT_Q(v) { sqp[0]+=(v).x; q2p[0]=fmaf((v).x,(v).x,q2p[0]); \
                    sqp[1]+=(v).y; q2p[1]=fmaf((v).y,(v).y,q2p[1]); \
                    sqp[2]+=(v).z; q2p[2]=fmaf((v).z,(v).z,q2p[2]); \
                    sqp[3]+=(v).w; q2p[3]=fmaf((v).w,(v).w,q2p[3]); }
#define STAT_P(v) { spp[0]+=(v).x; p2p[0]=fmaf((v).x,(v).x,p2p[0]); \
                    spp[1]+=(v).y; p2p[1]=fmaf((v).y,(v).y,p2p[1]); \
                    spp[2]+=(v).z; p2p[2]=fmaf((v).z,(v).z,p2p[2]); \
                    spp[3]+=(v).w; p2p[3]=fmaf((v).w,(v).w,p2p[3]); }

#define GRAM_CHUNK_BODY(NCHUNK_, QB_, PB_)                                     \
    for (int ch = 0; ch < (NCHUNK_); ++ch) {                                   \
        if (ch) __syncthreads();                                               \
        *(float4*)&stage[       ofs] = qv0;                                    \
        *(float4*)&stage[1024 + ofs] = qv1;                                    \
        *(float4*)&stage[2048 + ofs] = pv0;                                    \
        *(float4*)&stage[3072 + ofs] = pv1;                                    \
        float4 nq0, nq1, np0, np1;                                             \
        const bool more = (ch + 1 < (NCHUNK_));                                \
        if (more) {                                                            \
            const float* qn = (QB_) + (ch + 1) * 2048;                         \
            const float* pn = (PB_) + (ch + 1) * 2048;                         \
            nq0 = *(const float4*)(qn + ofs);                                  \
            nq1 = *(const float4*)(qn + 1024 + ofs);                           \
            np0 = *(const float4*)(pn + ofs);                                  \
            np1 = *(const float4*)(pn + 1024 + ofs);                           \
        }                                                                      \
        STAT_Q(qv0); STAT_Q(qv1);                                              \
        STAT_P(pv0); STAT_P(pv1);                                              \
        __syncthreads();                                                       \
        _Pragma("unroll 8")                                                    \
        for (int cc = 0; cc < CK; ++cc) {                                      \
            float4 a  = *(const float4*)&stage[cc * 64 + n0];                  \
            float4 bb = *(const float4*)&stage[2048 + cc * 64 + m0];           \
            acc[0][0]=fmaf(a.x,bb.x,acc[0][0]); acc[0][1]=fmaf(a.x,bb.y,acc[0][1]); \
            acc[0][2]=fmaf(a.x,bb.z,acc[0][2]); acc[0][3]=fmaf(a.x,bb.w,acc[0][3]); \
            acc[1][0]=fmaf(a.y,bb.x,acc[1][0]); acc[1][1]=fmaf(a.y,bb.y,acc[1][1]); \
            acc[1][2]=fmaf(a.y,bb.z,acc[1][2]); acc[1][3]=fmaf(a.y,bb.w,acc[1][3]); \
            acc[2][0]=fmaf(a.z,bb.x,acc[2][0]); acc[2][1]=fmaf(a.z,bb.y,acc[2][1]); \
            acc[2][2]=fmaf(a.z,bb.z,acc[2][2]); acc[2][3]=fmaf(a.z,bb.w,acc[2][3]); \
            acc[3][0]=fmaf(a.w,bb.x,acc[3][0]); acc[3][1]=fmaf(a.w,bb.y,acc[3][1]); \
            acc[3][2]=fmaf(a.w,bb.z,acc[3][2]); acc[3][3]=fmaf(a.w,bb.w,acc[3][3]); \
        }                                                                      \
        if (more) { qv0 = nq0; qv1 = nq1; pv0 = np0; pv1 = np1; }              \
    }

__global__ __launch_bounds__(256)
void deepemd_fused(const float* __restrict__ proto,
                   const float* __restrict__ query,
                   float* __restrict__ out)
{
    __shared__ __align__(16) float stage[2 * CK * NN];
    __shared__ __align__(16) float Kl [NN][68];
    __shared__ __align__(16) float KTl[NN][68];
    __shared__ __align__(16) float statL[4][NN];
    __shared__ __align__(16) float uL[NN];
    __shared__ __align__(16) float vL[NN];
    __shared__ __align__(16) float rL[NN];
    __shared__ __align__(16) float cL[NN];
    __shared__ float redl[4];

    const int b  = blockIdx.x;
    const int t  = threadIdx.x;
    const int tr = t >> 4, tc = t & 15;
    const int n0 = tr * 4, m0 = tc * 4;
    const int ofs = 4 * t;

    const float* __restrict__ pb = proto + (size_t)b * (NCH * NN);
    const float* __restrict__ qb = query + (size_t)b * (NCH * NN);

    float acc[4][4];
    #pragma unroll
    for (int i = 0; i < 4; ++i)
        #pragma unroll
        for (int j = 0; j < 4; ++j) acc[i][j] = 0.0f;
    float sqp[4] = {0,0,0,0}, q2p[4] = {0,0,0,0};
    float spp[4] = {0,0,0,0}, p2p[4] = {0,0,0,0};

    float4 qv0 = *(const float4*)(qb + ofs);
    float4 qv1 = *(const float4*)(qb + 1024 + ofs);
    float4 pv0 = *(const float4*)(pb + ofs);
    float4 pv1 = *(const float4*)(pb + 1024 + ofs);

    GRAM_CHUNK_BODY(NCH / CK, qb, pb)
    __syncthreads();

    #pragma unroll
    for (int i = 0; i < 4; ++i) {
        float s = acc[i][0] + acc[i][1] + acc[i][2] + acc[i][3];
        s += __shfl_xor(s, 1, 64); s += __shfl_xor(s, 2, 64);
        s += __shfl_xor(s, 4, 64); s += __shfl_xor(s, 8, 64);
        if (tc == 0) uL[n0 + i] = s;
    }
    #pragma unroll
    for (int k = 0; k < 4; ++k) {
        stage[t*16 +      k] = sqp[k];
        stage[t*16 +  4 + k] = q2p[k];
        stage[t*16 +  8 + k] = spp[k];
        stage[t*16 + 12 + k] = p2p[k];
    }
    __syncthreads();
    if (t < NN) {
        const int g = t >> 2, k = t & 3;
        float ssq = 0, sq2 = 0, ssp = 0, sp2 = 0;
        #pragma unroll
        for (int j = 0; j < 16; ++j) {
            const float* row = &stage[(j * 16 + g) * 16];
            ssq += row[k]; sq2 += row[4 + k]; ssp += row[8 + k]; sp2 += row[12 + k];
        }
        statL[0][t] = ssq; statL[1][t] = sq2; statL[2][t] = ssp; statL[3][t] = sp2;
    }
    __syncthreads();
    #pragma unroll
    for (int j = 0; j < 4; ++j)
        stage[tr * 64 + m0 + j] = acc[0][j] + acc[1][j] + acc[2][j] + acc[3][j];
    __syncthreads();
    if (t < NN) {
        float cs = 0;
        #pragma unroll
        for (int i = 0; i < 16; ++i) cs += stage[i * 64 + t];
        float w2 = fmaxf(cs * (1.0f/64.0f), 0.0f) + 0.001f;
        float w1 = fmaxf(uL[t] * (1.0f/64.0f), 0.0f) + 0.001f;
        float s1 = w1, s2 = w2;
        #pragma unroll
        for (int m = 1; m < 64; m <<= 1) {
            s1 += __shfl_xor(s1, m, 64);
            s2 += __shfl_xor(s2, m, 64);
        }
        rL[t] = w1 / s1;
        cL[t] = w2 / s2;
        vL[t] = 1.0f;
    }
    __syncthreads();

    {
        float nq_[4], np_[4], sqn[4], spm[4];
        #pragma unroll
        for (int i = 0; i < 4; ++i) {
            float sv  = statL[0][n0 + i];
            float var = statL[1][n0 + i] - sv * sv * (1.0f/1024.0f);
            nq_[i] = fmaxf(sqrtf(fmaxf(var, 0.0f)), 1e-8f);
            sqn[i] = sv;
        }
        #pragma unroll
        for (int j = 0; j < 4; ++j) {
            float sv  = statL[2][m0 + j];
            float var = statL[3][m0 + j] - sv * sv * (1.0f/1024.0f);
            np_[j] = fmaxf(sqrtf(fmaxf(var, 0.0f)), 1e-8f);
            spm[j] = sv;
        }
        #pragma unroll
        for (int i = 0; i < 4; ++i) {
            #pragma unroll
            for (int j = 0; j < 4; ++j) {
                float sim = (acc[i][j] - sqn[i] * spm[j] * (1.0f/1024.0f)) / (nq_[i] * np_[j]);
                acc[i][j] = sim;
                float Kv = exp2f((sim - 1.0f) * KSC);
                Kl [n0 + i][m0 + j] = Kv;
                KTl[m0 + j][n0 + i] = Kv;
            }
        }
    }
    __syncthreads();

    const int sn  = t >> 2;
    const int sp4 = t & 3;
    float Kr[16], KTr[16];
    #pragma unroll
    for (int jj = 0; jj < 4; ++jj) {
        float4 kv = *(const float4*)&Kl [sn][sp4 * 16 + jj * 4];
        float4 kt = *(const float4*)&KTl[sn][sp4 * 16 + jj * 4];
        Kr [jj*4+0]=kv.x; Kr [jj*4+1]=kv.y; Kr [jj*4+2]=kv.z; Kr [jj*4+3]=kv.w;
        KTr[jj*4+0]=kt.x; KTr[jj*4+1]=kt.y; KTr[jj*4+2]=kt.z; KTr[jj*4+3]=kt.w;
    }
    const float rreg = rL[sn];
    const float creg = cL[sn];

    for (int it = 0; it < 100; ++it) {
        float s = DOT16(Kr, vL);
        s += __shfl_xor(s, 1, 64); s += __shfl_xor(s, 2, 64);
        float u = rreg / fmaxf(s, 1e-30f);
        if (sp4 == 0) uL[sn] = u;
        __syncthreads();
        float s2 = DOT16(KTr, uL);
        s2 += __shfl_xor(s2, 1, 64); s2 += __shfl_xor(s2, 2, 64);
        float vv = creg / fmaxf(s2, 1e-30f);
        if (sp4 == 0) vL[sn] = vv;
        __syncthreads();
    }
    {
        float s = DOT16(Kr, vL);
        s += __shfl_xor(s, 1, 64); s += __shfl_xor(s, 2, 64);
        float u = rreg / fmaxf(s, 1e-30f);
        if (sp4 == 0) uL[sn] = u;
    }
    __syncthreads();

    float uu[4], vv_[4];
    #pragma unroll
    for (int i = 0; i < 4; ++i) uu[i]  = uL[n0 + i];
    #pragma unroll
    for (int j = 0; j < 4; ++j) vv_[j] = vL[m0 + j];
    float part = 0.0f;
    #pragma unroll
    for (int i = 0; i < 4; ++i) {
        #pragma unroll
        for (int j = 0; j < 4; ++j) {
            float sim = acc[i][j];
            float Kv  = exp2f((sim - 1.0f) * KSC);
            part = fmaf(sim * Kv, uu[i] * vv_[j], part);
        }
    }
    #pragma unroll
    for (int m = 1; m < 64; m <<= 1) part += __shfl_xor(part, m, 64);
    if ((t & 63) == 0) redl[t >> 6] = part;
    __syncthreads();
    if (t == 0) out[b] = (redl[0] + redl[1] + redl[2] + redl[3]) * (12.5f / 64.0f);
}

extern "C" void kernel_launch(void* const* d_in, const int* in_sizes, int n_in,
                              void* d_out, int out_size, void* d_ws, size_t ws_size,
                              hipStream_t stream) {
    const float* proto = (const float*)d_in[0];
    const float* query = (const float*)d_in[1];
    float* out = (float*)d_out;
    (void)in_sizes; (void)n_in; (void)out_size;

    const size_t need = (size_t)512 * SPLIT * WSB * sizeof(float);   // ~17.8 MB
    if (ws_size >= need) {
        gram4    <<<dim3(512 * SPLIT), dim3(256), 0, stream>>>(proto, query, (float*)d_ws);
        emd_solve<<<dim3(512),         dim3(256), 0, stream>>>((const float*)d_ws, out);
    } else {
        deepemd_fused<<<dim3(512), dim3(256), 0, stream>>>(proto, query, out);
    }
}